// Round 1
// baseline (2686.138 us; speedup 1.0000x reference)
//
#include <hip/hip_runtime.h>

#ifndef __has_builtin
#define __has_builtin(x) 0
#endif

#define DEV static __device__ __forceinline__

// problem dims
#define TT 128
#define BB 256
#define HH 128
#define KK 64
#define VV 128
#define OO 512
#define JBLK 132                // 128 hypernet j-blocks + 4 blocks holding hyp_b2
#define KEXT (JBLK*32)          // 4224

static const size_t PRED_OFF  = 0;
static const size_t LOGIT_OFF = (size_t)TT*BB*OO;                  // 16777216
static const size_t INFH_OFF  = LOGIT_OFF + (size_t)TT*BB*OO;      // 33554432
static const size_t GEN_OFF   = INFH_OFF + (size_t)TT*BB*HH;       // 37748736
static const size_t GATE_OFF  = GEN_OFF + (size_t)TT*BB*HH;        // 41943040

DEV unsigned short f2bf(float x){
  unsigned int u = __float_as_uint(x);
  u = (u + 0x7fffu + ((u >> 16) & 1u)) >> 16;   // RNE
  return (unsigned short)u;
}
DEV float bf2f(unsigned short v){ return __uint_as_float(((unsigned int)v) << 16); }

// ---------------- fp8 e4m3 helpers (HW builtins with software fallback) -------------
#if __has_builtin(__builtin_amdgcn_cvt_pk_f32_fp8)
#define FP8_FAST_DEC 1
typedef float floatx2 __attribute__((ext_vector_type(2)));
#endif

DEV float dec8_sw(unsigned int b){
  unsigned int s = b >> 7, e = (b >> 3) & 15u, m = b & 7u;
  float v = e ? ldexpf((float)(8u + m), (int)e - 10) : ldexpf((float)m, -9);
  return s ? -v : v;
}

DEV unsigned char enc8_sw(float x){
  unsigned int u = __float_as_uint(x);
  unsigned int s = (u >> 24) & 0x80u;
  int e = (int)((u >> 23) & 0xffu) - 127;
  unsigned int m = u & 0x7fffffu;
  if (((u >> 23) & 0xffu) == 0) return (unsigned char)s;    // zero/denorm input -> 0
  if (e < -10) return (unsigned char)s;
  if (e >= -6) {
    unsigned int mant = m >> 20, rem = m & 0xfffffu;
    if (rem > 0x80000u || (rem == 0x80000u && (mant & 1u))) mant++;
    unsigned int ee = (unsigned int)(e + 7);
    if (mant == 8u) { mant = 0u; ee++; }
    if (ee >= 15u) return (unsigned char)(s | 0x7Eu);       // clamp to 448
    return (unsigned char)(s | (ee << 3) | mant);
  }
  // subnormal output, e in [-10,-7]
  unsigned int full = 0x800000u | m;
  int sh = 20 + (-6 - e);                                   // 21..24
  unsigned int mant = full >> sh;
  unsigned int rem  = full & ((1u << sh) - 1u);
  unsigned int halfv = 1u << (sh - 1);
  if (rem > halfv || (rem == halfv && (mant & 1u))) mant++;
  if (mant >= 8u) return (unsigned char)(s | (1u << 3));
  return (unsigned char)(s | mant);
}

DEV unsigned char enc8(float v){
#if __has_builtin(__builtin_amdgcn_cvt_pk_fp8_f32)
  int r = __builtin_amdgcn_cvt_pk_fp8_f32(v, v, 0, false);
  return (unsigned char)(r & 0xff);
#else
  return enc8_sw(v);
#endif
}

// ---------------- K0: pack W2ext (hyp_W2 | hyp_b2) to fp8, x1024, frag layout ----------
// byte (j,n,h,ig,bb) at ((j*8 + n*2 + h)*32 + ig)*16 + bb ; i = ig*4+n ; k = j*32+h*16+bb
__global__ __launch_bounds__(256) void k_pack(const float* __restrict__ hW2,
                                              const float* __restrict__ hb2,
                                              unsigned char* __restrict__ w2p){
  int D = blockIdx.x * 256 + threadIdx.x;        // dword index
  if (D >= KEXT * HH / 4) return;
  int bq = D & 3;
  int ig = (D >> 2) & 31;
  int h  = (D >> 7) & 1;
  int n  = (D >> 8) & 3;
  int j  = D >> 10;
  int i  = ig * 4 + n;
  unsigned int outw = 0;
  for (int c = 0; c < 4; ++c) {
    int bb = bq * 4 + c;
    int k = j * 32 + h * 16 + bb;
    float v;
    if (j < 128) v = hW2[((size_t)i * HH + j) * 32 + (k & 31)];
    else         v = hb2[(size_t)i * HH + (k - 4096)];
    v *= 1024.0f;
    outw |= ((unsigned int)enc8(v)) << (8 * c);
  }
  ((unsigned int*)w2p)[D] = outw;
}

// ---------------- K1: sequential scan (hidden recurrence only) -------------------------
struct ScanSmem {
  unsigned short gw[128 * 258];   // gate_W bf16, padded stride
  float part[16 * 128];
  float x[256];
  float pi[128];
  float i2h[128];
  float h[128];
  float hyp[32];
  float velWs[HH * 3];
  float velbs[HH];
  float hypW1s[32 * 3];
  float hypb1s[32];
  float gbs[HH];
  float vel3[4];
};

__global__ __launch_bounds__(512) void k_scan(
    const int* __restrict__ obs, const float* __restrict__ vel,
    const float* __restrict__ hinit, const float* __restrict__ embW,
    const float* __restrict__ velW, const float* __restrict__ velb,
    const float* __restrict__ hW1, const float* __restrict__ hb1,
    const float* __restrict__ gW, const float* __restrict__ gb,
    const unsigned char* __restrict__ w2p,
    float* __restrict__ out)
{
  extern __shared__ char smemraw[];
  ScanSmem* sm = (ScanSmem*)smemraw;
  const int tid = threadIdx.x;
  const int b = blockIdx.x;

  for (int idx = tid; idx < 128 * 256; idx += 512) {
    int i = idx >> 8, c = idx & 255;
    sm->gw[i * 258 + c] = f2bf(gW[i * 256 + c]);
  }
  for (int idx = tid; idx < HH * 3; idx += 512) sm->velWs[idx] = velW[idx];
  for (int idx = tid; idx < HH; idx += 512) { sm->velbs[idx] = velb[idx]; sm->gbs[idx] = gb[idx]; }
  for (int idx = tid; idx < 96; idx += 512) sm->hypW1s[idx] = hW1[idx];
  if (tid < 32) sm->hypb1s[tid] = hb1[tid];
  if (tid < 128) sm->h[tid] = tanhf(hinit[tid]);
  __syncthreads();

  const int ig = tid & 31;          // group of 4 output rows i = ig*4..ig*4+3
  const int ks = tid >> 5;          // j-slice 0..15
  const int jbeg = ks * 8 + (ks < 4 ? ks : 4);
  const int jend = jbeg + 8 + (ks < 4 ? 1 : 0);

  for (int t = 0; t < TT; ++t) {
    if (tid < 3) sm->vel3[tid] = vel[((size_t)t * BB + b) * 3 + tid];
    if (tid >= 128 && tid < 256) {
      int j = tid - 128;
      sm->i2h[j] = embW[(size_t)obs[t * BB + b] * HH + j];
    }
    __syncthreads();
    if (tid < 32) {
      float a = sm->vel3[0] * sm->hypW1s[tid * 3] + sm->vel3[1] * sm->hypW1s[tid * 3 + 1]
              + sm->vel3[2] * sm->hypW1s[tid * 3 + 2] + sm->hypb1s[tid];
      sm->hyp[tid] = a / (1.0f + __expf(-a));          // silu
    }
    __syncthreads();

    float hypr[32];
    #pragma unroll
    for (int d = 0; d < 32; d += 4) {
      float4 q4 = *(const float4*)&sm->hyp[d];
      hypr[d] = q4.x; hypr[d + 1] = q4.y; hypr[d + 2] = q4.z; hypr[d + 3] = q4.w;
    }

    float acc0 = 0.f, acc1 = 0.f, acc2 = 0.f, acc3 = 0.f;
    for (int j = jbeg; j < jend; ++j) {
      float uj[32];
      if (j < 128) {
        float hj = sm->h[j];
        #pragma unroll
        for (int d = 0; d < 32; ++d) uj[d] = hj * hypr[d];
      } else {
        int base = (j - 128) * 32;
        #pragma unroll
        for (int d = 0; d < 32; d += 4) {
          float4 q4 = *(const float4*)&sm->h[base + d];
          uj[d] = q4.x; uj[d + 1] = q4.y; uj[d + 2] = q4.z; uj[d + 3] = q4.w;
        }
      }
      const unsigned char* pj = w2p + (size_t)j * 4096 + (size_t)ig * 16;
      #pragma unroll
      for (int n = 0; n < 4; ++n) {
        uint4 wa = *(const uint4*)(pj + (n * 2 + 0) * 512);
        uint4 wb = *(const uint4*)(pj + (n * 2 + 1) * 512);
        const unsigned int* wpa = (const unsigned int*)&wa;
        const unsigned int* wpb = (const unsigned int*)&wb;
        float s = 0.f;
        #pragma unroll
        for (int q = 0; q < 4; ++q) {
          unsigned int ww = wpa[q];
#if defined(FP8_FAST_DEC)
          floatx2 lo = __builtin_amdgcn_cvt_pk_f32_fp8((int)ww, false);
          floatx2 hi = __builtin_amdgcn_cvt_pk_f32_fp8((int)ww, true);
          s += lo[0]*uj[q*4+0] + lo[1]*uj[q*4+1] + hi[0]*uj[q*4+2] + hi[1]*uj[q*4+3];
#else
          s += dec8_sw(ww & 0xffu)        * uj[q*4+0];
          s += dec8_sw((ww >> 8) & 0xffu) * uj[q*4+1];
          s += dec8_sw((ww >> 16) & 0xffu)* uj[q*4+2];
          s += dec8_sw((ww >> 24) & 0xffu)* uj[q*4+3];
#endif
        }
        #pragma unroll
        for (int q = 0; q < 4; ++q) {
          unsigned int ww = wpb[q];
#if defined(FP8_FAST_DEC)
          floatx2 lo = __builtin_amdgcn_cvt_pk_f32_fp8((int)ww, false);
          floatx2 hi = __builtin_amdgcn_cvt_pk_f32_fp8((int)ww, true);
          s += lo[0]*uj[16+q*4+0] + lo[1]*uj[16+q*4+1] + hi[0]*uj[16+q*4+2] + hi[1]*uj[16+q*4+3];
#else
          s += dec8_sw(ww & 0xffu)        * uj[16+q*4+0];
          s += dec8_sw((ww >> 8) & 0xffu) * uj[16+q*4+1];
          s += dec8_sw((ww >> 16) & 0xffu)* uj[16+q*4+2];
          s += dec8_sw((ww >> 24) & 0xffu)* uj[16+q*4+3];
#endif
        }
        if (n == 0) acc0 += s; else if (n == 1) acc1 += s; else if (n == 2) acc2 += s; else acc3 += s;
      }
    }
    *(float4*)&sm->part[ks * 128 + ig * 4] = make_float4(acc0, acc1, acc2, acc3);
    __syncthreads();

    if (tid < 128) {
      float s = 0.f;
      #pragma unroll
      for (int q = 0; q < 16; ++q) s += sm->part[q * 128 + tid];
      s *= (1.0f / 1024.0f);
      s += sm->vel3[0] * sm->velWs[tid * 3] + sm->vel3[1] * sm->velWs[tid * 3 + 1]
         + sm->vel3[2] * sm->velWs[tid * 3 + 2] + sm->velbs[tid];
      sm->pi[tid] = s;
      sm->x[tid] = s;
      out[GEN_OFF + ((size_t)t * BB + b) * HH + tid] = s;
    } else if (tid < 256) {
      sm->x[tid] = sm->i2h[tid - 128];
    }
    __syncthreads();

    {
      int i = tid & 127, kq = tid >> 7;
      const unsigned short* gr = &sm->gw[i * 258 + kq * 64];
      const float* xr = &sm->x[kq * 64];
      float s = 0.f;
      #pragma unroll 16
      for (int c = 0; c < 64; ++c) s += bf2f(gr[c]) * xr[c];
      sm->part[kq * 128 + i] = s;
    }
    __syncthreads();

    if (tid < 128) {
      float z = sm->part[tid] + sm->part[128 + tid] + sm->part[256 + tid] + sm->part[384 + tid] + sm->gbs[tid];
      float g = 1.0f / (1.0f + __expf(-z));
      float hn = tanhf(g * sm->pi[tid] + (1.0f - g) * sm->i2h[tid]);
      out[GATE_OFF + ((size_t)t * BB + b) * HH + tid] = g;
      out[INFH_OFF + ((size_t)t * BB + b) * HH + tid] = hn;
      sm->h[tid] = hn;
    }
    __syncthreads();
  }
}

// ---------------- K2a1: q / keys / vals projections (parallel over t) ------------------
struct QkvSmem {
  float wqk[64 * 132];
  float wv[128 * 132];
  float pp[132];
  float hh[132];
  float red[4];
  float stats[2];
};

__global__ __launch_bounds__(256) void k_qkv(const float* __restrict__ out,
    const float* __restrict__ Wqk, const float* __restrict__ Wv,
    float* __restrict__ qbuf, unsigned short* __restrict__ keysBF,
    unsigned short* __restrict__ valsBF)
{
  extern __shared__ char smemraw[];
  QkvSmem* sm = (QkvSmem*)smemraw;
  const int tid = threadIdx.x, b = blockIdx.x;

  for (int idx = tid; idx < 64 * 128; idx += 256) { int o = idx >> 7, j = idx & 127; sm->wqk[o * 132 + j] = Wqk[idx]; }
  for (int idx = tid; idx < 128 * 128; idx += 256) { int o = idx >> 7, j = idx & 127; sm->wv[o * 132 + j] = Wv[idx]; }
  __syncthreads();

  for (int t = 0; t < TT; ++t) {
    if (tid < 128) {
      size_t base = ((size_t)t * BB + b) * HH + tid;
      sm->hh[tid] = out[INFH_OFF + base];
      sm->pp[tid] = tanhf(out[GEN_OFF + base]);
    }
    __syncthreads();
    if (tid < 128) {
      float v = sm->pp[tid];
      float s1 = v, s2 = v * v;
      #pragma unroll
      for (int off = 32; off; off >>= 1) { s1 += __shfl_down(s1, off); s2 += __shfl_down(s2, off); }
      if ((tid & 63) == 0) { sm->red[tid >> 6] = s1; sm->red[2 + (tid >> 6)] = s2; }
    }
    __syncthreads();
    if (tid == 0) {
      float s1 = sm->red[0] + sm->red[1], s2 = sm->red[2] + sm->red[3];
      float m = s1 * (1.0f / 128.0f);
      float var = s2 * (1.0f / 128.0f) - m * m;
      sm->stats[0] = m; sm->stats[1] = rsqrtf(var + 1e-5f);
    }
    __syncthreads();
    if (tid < 128) sm->pp[tid] = (sm->pp[tid] - sm->stats[0]) * sm->stats[1];
    __syncthreads();
    {
      int o = tid;
      if (o < 64) {
        const float* wr = &sm->wqk[o * 132];
        float s = 0.f;
        #pragma unroll 8
        for (int j = 0; j < 128; j += 4) {
          float4 xv = *(const float4*)&sm->pp[j];
          float4 w4 = *(const float4*)&wr[j];
          s += xv.x * w4.x + xv.y * w4.y + xv.z * w4.z + xv.w * w4.w;
        }
        qbuf[((size_t)t * BB + b) * KK + o] = s;
      } else if (o < 128) {
        int kk = o - 64;
        const float* wr = &sm->wqk[kk * 132];
        float s = 0.f;
        #pragma unroll 8
        for (int j = 0; j < 128; j += 4) {
          float4 xv = *(const float4*)&sm->hh[j];
          float4 w4 = *(const float4*)&wr[j];
          s += xv.x * w4.x + xv.y * w4.y + xv.z * w4.z + xv.w * w4.w;
        }
        keysBF[((size_t)t * BB + b) * KK + kk] = f2bf(s);
      } else {
        int vv = o - 128;
        const float* wr = &sm->wv[vv * 132];
        float s = 0.f;
        #pragma unroll 8
        for (int j = 0; j < 128; j += 4) {
          float4 xv = *(const float4*)&sm->hh[j];
          float4 w4 = *(const float4*)&wr[j];
          s += xv.x * w4.x + xv.y * w4.y + xv.z * w4.z + xv.w * w4.w;
        }
        valsBF[((size_t)t * BB + b) * VV + vv] = f2bf(s);
      }
    }
    __syncthreads();
  }
}

// ---------------- K2a2: all scores + max_ip + write-prob MLP ---------------------------
struct ScoresSmem { float q[128 * 68]; };

__global__ __launch_bounds__(128) void k_scores(const float* __restrict__ qbuf,
    const unsigned short* __restrict__ keysBF, const float* __restrict__ expl,
    const float* __restrict__ mW1, const float* __restrict__ mb1,
    const float* __restrict__ mW2, const float* __restrict__ mb2,
    float* __restrict__ Sg, float* __restrict__ probs)
{
  extern __shared__ char smemraw[];
  ScoresSmem* sm = (ScoresSmem*)smemraw;
  const int tid = threadIdx.x, b = blockIdx.x;

  for (int idx = tid; idx < 128 * 64; idx += 128) {
    int tq = idx >> 6, c = idx & 63;
    sm->q[tq * 68 + c] = qbuf[((size_t)tq * BB + b) * KK + c];
  }
  float kreg[64];
  {
    const uint4* kp = (const uint4*)&keysBF[((size_t)tid * BB + b) * KK];
    #pragma unroll
    for (int qq = 0; qq < 8; ++qq) {
      uint4 kv = kp[qq];
      const unsigned short* ku = (const unsigned short*)&kv;
      #pragma unroll
      for (int c = 0; c < 8; ++c) kreg[qq * 8 + c] = bf2f(ku[c]);
    }
  }
  __syncthreads();

  float* srow = &Sg[(size_t)b * TT * TT];
  for (int tq = 0; tq < TT; ++tq) {
    float s = 0.f;
    #pragma unroll
    for (int c = 0; c < 64; c += 4) {
      float4 qv = *(const float4*)&sm->q[tq * 68 + c];
      s += qv.x * kreg[c] + qv.y * kreg[c + 1] + qv.z * kreg[c + 2] + qv.w * kreg[c + 3];
    }
    srow[(size_t)tq * TT + tid] = s * 0.125f;     // scale = 1/sqrt(64)
  }
  __syncthreads();

  {
    int tq = tid;
    const float* r = &srow[(size_t)tq * TT];
    float mx = -3.0e38f;
    for (int tk = 0; tk < tq; ++tk) mx = fmaxf(mx, r[tk]);
    float f0 = (tq > 0) ? mx : 0.0f;              // max_ip * has_mem
    float f1 = (float)tq * (1.0f / 128.0f);
    float f2 = expl[(size_t)tq * BB + b];
    float a = 0.f;
    for (int u = 0; u < 200; ++u) {
      float h1 = mW1[u * 3] * f0 + mW1[u * 3 + 1] * f1 + mW1[u * 3 + 2] * f2 + mb1[u];
      h1 = (h1 > 0.f) ? h1 : 0.1f * h1;           // leaky_relu 0.1
      a += mW2[u] * h1;
    }
    float p = 1.0f / (1.0f + __expf(-(a + mb2[0])));
    probs[(size_t)b * TT + tq] = p;
  }
}

// ---------------- K2b: softmax·probs·vals -> LN -> logits -> preds ---------------------
struct AttnSmem {
  float w[32 * 132];
  float mem[32 * 132];
  float pw[128 * 132];
};

__global__ __launch_bounds__(256) void k_attn(const float* __restrict__ Sg,
    const float* __restrict__ probs, const unsigned short* __restrict__ valsBF,
    const float* __restrict__ pW, const float* __restrict__ pb,
    float* __restrict__ out)
{
  extern __shared__ char smemraw[];
  AttnSmem* sm = (AttnSmem*)smemraw;
  const int tid = threadIdx.x;
  const int t = blockIdx.x >> 3, g = blockIdx.x & 7;
  const int bloc = tid >> 3, s8 = tid & 7;
  const int b = g * 32 + bloc;

  float acc[16];
  #pragma unroll
  for (int c = 0; c < 16; ++c) acc[c] = 0.f;

  float inv = 0.f;
  if (t > 0) {
    const float* srow = &Sg[((size_t)b * TT + t) * TT];
    float mx = -3.0e38f;
    for (int tk = s8; tk < t; tk += 8) mx = fmaxf(mx, srow[tk]);
    #pragma unroll
    for (int off = 4; off; off >>= 1) mx = fmaxf(mx, __shfl_xor(mx, off, 8));
    float es = 0.f;
    for (int tk = s8; tk < t; tk += 8) {
      float e = __expf(srow[tk] - mx);
      es += e;
      sm->w[bloc * 132 + tk] = e * probs[(size_t)b * TT + tk];
    }
    #pragma unroll
    for (int off = 4; off; off >>= 1) es += __shfl_xor(es, off, 8);
    inv = 1.0f / es;
  }
  __syncthreads();
  if (t > 0) {
    for (int tk = 0; tk < t; ++tk) {
      float wv = sm->w[bloc * 132 + tk] * inv;
      const uint4* vp = (const uint4*)&valsBF[((size_t)tk * BB + b) * VV + s8 * 16];
      uint4 v0 = vp[0], v1 = vp[1];
      const unsigned short* u0 = (const unsigned short*)&v0;
      const unsigned short* u1 = (const unsigned short*)&v1;
      #pragma unroll
      for (int c = 0; c < 8; ++c) acc[c] += wv * bf2f(u0[c]);
      #pragma unroll
      for (int c = 0; c < 8; ++c) acc[8 + c] += wv * bf2f(u1[c]);
    }
  }
  // layer-norm over the 128 components (8 lanes x 16 each)
  float s1 = 0.f, s2 = 0.f;
  #pragma unroll
  for (int c = 0; c < 16; ++c) { s1 += acc[c]; s2 += acc[c] * acc[c]; }
  #pragma unroll
  for (int off = 4; off; off >>= 1) { s1 += __shfl_xor(s1, off, 8); s2 += __shfl_xor(s2, off, 8); }
  float m = s1 * (1.0f / 128.0f);
  float var = s2 * (1.0f / 128.0f) - m * m;
  float sc = rsqrtf(var + 1e-5f);
  #pragma unroll
  for (int c = 0; c < 16; ++c) sm->mem[bloc * 132 + s8 * 16 + c] = (acc[c] - m) * sc;
  __syncthreads();

  const int og = tid >> 5, bl2 = tid & 31;
  const int b2 = g * 32 + bl2;
  for (int st = 0; st < 4; ++st) {
    for (int idx = tid; idx < 128 * 128; idx += 256) {
      int o = idx >> 7, i = idx & 127;
      sm->pw[o * 132 + i] = pW[((size_t)(st * 128 + o)) * HH + i];
    }
    __syncthreads();
    #pragma unroll
    for (int ob = 0; ob < 4; ++ob) {
      int oo = og * 16 + ob * 4;
      float a0 = pb[st * 128 + oo], a1 = pb[st * 128 + oo + 1];
      float a2 = pb[st * 128 + oo + 2], a3 = pb[st * 128 + oo + 3];
      for (int i = 0; i < 128; i += 4) {
        float4 mv = *(const float4*)&sm->mem[bl2 * 132 + i];
        float4 w0 = *(const float4*)&sm->pw[(oo + 0) * 132 + i];
        float4 w1 = *(const float4*)&sm->pw[(oo + 1) * 132 + i];
        float4 w2 = *(const float4*)&sm->pw[(oo + 2) * 132 + i];
        float4 w3 = *(const float4*)&sm->pw[(oo + 3) * 132 + i];
        a0 += mv.x * w0.x + mv.y * w0.y + mv.z * w0.z + mv.w * w0.w;
        a1 += mv.x * w1.x + mv.y * w1.y + mv.z * w1.z + mv.w * w1.w;
        a2 += mv.x * w2.x + mv.y * w2.y + mv.z * w2.z + mv.w * w2.w;
        a3 += mv.x * w3.x + mv.y * w3.y + mv.z * w3.z + mv.w * w3.w;
      }
      size_t base = LOGIT_OFF + ((size_t)t * BB + b2) * OO + st * 128 + oo;
      out[base] = a0; out[base + 1] = a1; out[base + 2] = a2; out[base + 3] = a3;
    }
    __syncthreads();
  }
  // preds = softmax(logits) over O
  {
    const float* lrow = &out[LOGIT_OFF + ((size_t)t * BB + b) * OO];
    float mx = -3.0e38f;
    for (int o = s8; o < OO; o += 8) mx = fmaxf(mx, lrow[o]);
    #pragma unroll
    for (int off = 4; off; off >>= 1) mx = fmaxf(mx, __shfl_xor(mx, off, 8));
    float zs = 0.f;
    for (int o = s8; o < OO; o += 8) zs += __expf(lrow[o] - mx);
    #pragma unroll
    for (int off = 4; off; off >>= 1) zs += __shfl_xor(zs, off, 8);
    float zi = 1.0f / zs;
    float* prow = &out[PRED_OFF + ((size_t)t * BB + b) * OO];
    for (int o = s8; o < OO; o += 8) prow[o] = __expf(lrow[o] - mx) * zi;
  }
}

// ---------------- launcher -------------------------------------------------------------
extern "C" void kernel_launch(void* const* d_in, const int* in_sizes, int n_in,
                              void* d_out, int out_size, void* d_ws, size_t ws_size,
                              hipStream_t stream) {
  (void)in_sizes; (void)n_in; (void)out_size; (void)ws_size;
  const int*   obs   = (const int*)d_in[0];
  const float* vel   = (const float*)d_in[1];
  const float* expl  = (const float*)d_in[2];
  const float* hinit = (const float*)d_in[3];
  const float* embW  = (const float*)d_in[4];
  const float* velW  = (const float*)d_in[5];
  const float* velb  = (const float*)d_in[6];
  const float* hW1   = (const float*)d_in[7];
  const float* hb1   = (const float*)d_in[8];
  const float* hW2   = (const float*)d_in[9];
  const float* hb2   = (const float*)d_in[10];
  const float* gW    = (const float*)d_in[11];
  const float* gb    = (const float*)d_in[12];
  const float* pW    = (const float*)d_in[13];
  const float* pb    = (const float*)d_in[14];
  const float* mW1   = (const float*)d_in[15];
  const float* mb1   = (const float*)d_in[16];
  const float* mW2   = (const float*)d_in[17];
  const float* mb2   = (const float*)d_in[18];
  const float* Wqk   = (const float*)d_in[19];
  const float* Wv    = (const float*)d_in[20];
  float* out = (float*)d_out;
  char* ws = (char*)d_ws;

  unsigned char*  w2p    = (unsigned char*)(ws + 0);            // 540,672 B
  float*          qbuf   = (float*)(ws + 1048576);              // 8 MB
  unsigned short* keysBF = (unsigned short*)(ws + 9437184);     // 4 MB
  unsigned short* valsBF = (unsigned short*)(ws + 13631488);    // 8 MB
  float*          Sg     = (float*)(ws + 22020096);             // 16 MB
  float*          probs  = (float*)(ws + 38797312);             // 128 KB (total ~37.1 MB)

  k_pack  <<<dim3(528),  dim3(256), 0,                  stream>>>(hW2, hb2, w2p);
  k_scan  <<<dim3(256),  dim3(512), sizeof(ScanSmem),   stream>>>(obs, vel, hinit, embW, velW, velb,
                                                                  hW1, hb1, gW, gb, w2p, out);
  k_qkv   <<<dim3(256),  dim3(256), sizeof(QkvSmem),    stream>>>(out, Wqk, Wv, qbuf, keysBF, valsBF);
  k_scores<<<dim3(256),  dim3(128), sizeof(ScoresSmem), stream>>>(qbuf, keysBF, expl, mW1, mb1, mW2, mb2,
                                                                  Sg, probs);
  k_attn  <<<dim3(1024), dim3(256), sizeof(AttnSmem),   stream>>>(Sg, probs, valsBF, pW, pb, out);
}